// Round 17
// baseline (150.559 us; speedup 1.0000x reference)
//
#include <hip/hip_runtime.h>

typedef float f32x4 __attribute__((ext_vector_type(4)));
typedef short bf16x8 __attribute__((ext_vector_type(8)));

#define NN 16384
#define NCB 8
#define DIM 32
#define CB 1024
#define RPB 512
#define EPP 512  // entries per pass (LDS holds 3 bf16 planes of EPP x DIM)
#define TPP 32   // 16-entry tiles per pass

// raw barrier: cross-wave LDS ordering only -- does NOT drain vmcnt (stores
// stay in flight; __syncthreads would stall ~1MB/block of zero-stores here)
#define LGK_BARRIER() \
    asm volatile("s_waitcnt lgkmcnt(0)\n\ts_barrier" ::: "memory")

// fp32 -> bf16 RTNE on the bit pattern (finite data only)
__device__ __forceinline__ unsigned short f2bf(float v) {
    const unsigned u = __float_as_uint(v);
    return (unsigned short)((u + 0x7FFFu + ((u >> 16) & 1u)) >> 16);
}
__device__ __forceinline__ float bf2f(unsigned short s) {
    return __uint_as_float(((unsigned)s) << 16);
}

// split x into 3 bf16 planes: x = h + m + l + r, |r| <= 2^-27 |x|
__device__ __forceinline__ void split3(const f32x4 a, const f32x4 b,
                                       bf16x8* H, bf16x8* M, bf16x8* L) {
    bf16x8 h, m, l;
#pragma unroll
    for (int j = 0; j < 8; ++j) {
        const float vv = (j < 4) ? a[j] : b[j - 4];
        const unsigned short hs = f2bf(vv);
        const float r1 = vv - bf2f(hs);  // exact
        const unsigned short ms = f2bf(r1);
        const float r2 = r1 - bf2f(ms);  // exact
        h[j] = (short)hs;
        m[j] = (short)ms;
        l[j] = (short)f2bf(r2);
    }
    *H = h;
    *M = m;
    *L = l;
}

// csqb[k*CB+c] = ||codebook[k,c]||^2 + rate_bias[k,c]  (frozen fp32 chain)
__global__ __launch_bounds__(256) void vq_csq(const float* __restrict__ cb,
                                              const float* __restrict__ rb,
                                              float* __restrict__ out) {
    int i = blockIdx.x * 256 + threadIdx.x;
    if (i >= NCB * CB) return;
    const f32x4* c4 = (const f32x4*)(cb + (size_t)i * DIM);
    float s0 = 0.f, s1 = 0.f, s2 = 0.f, s3 = 0.f;
#pragma unroll
    for (int j = 0; j < 8; ++j) {
        f32x4 v = c4[j];
        s0 = fmaf(v[0], v[0], s0);
        s1 = fmaf(v[1], v[1], s1);
        s2 = fmaf(v[2], v[2], s2);
        s3 = fmaf(v[3], v[3], s3);
    }
    out[i] = ((s0 + s1) + (s2 + s3)) + rb[i];
}

// Fused MFMA kernel (R16 structure + drain fixes):
//   - pass-1 codebook prefetched to REGISTERS before any zero-store: the
//     loads are the OLDEST vmcnt FIFO entries, so their consumption at
//     restage is a counted wait that never drains the stores behind them.
//   - restage barriers are lgkmcnt-only (raw s_barrier): zero-stores fly
//     through both passes and are drained exactly once, at the end.
//   - launch_bounds(512,1): 101 KB LDS already pins 1 block/CU; free regalloc.
// Numerics bit-identical to R16 (passed absmax 0.0): 6-MFMA 3-plane bf16
// split, dist = fmaf(-2, acc, cq), strict < + lexicographic reduce.
__global__ __launch_bounds__(512, 1) void vq_fused(
    const float* __restrict__ x, const float* __restrict__ cb,
    const float* __restrict__ csqb, float* __restrict__ xhat,
    float* __restrict__ onehot, float* __restrict__ idxf) {
    __shared__ short cH[EPP * DIM];       // 32 KB
    __shared__ short cM[EPP * DIM];       // 32 KB
    __shared__ short cL[EPP * DIM];       // 32 KB
    __shared__ float sCq[CB];             // 4 KB
    __shared__ unsigned short sIdx[RPB];  // 1 KB   -> ~101 KB: 1 block/CU

    const int tid = threadIdx.x;
    const int w = tid >> 6;
    const int lane = tid & 63;
    const int l15 = lane & 15;
    const int l4 = lane >> 4;
    const int k = blockIdx.x & (NCB - 1);
    const int n0 = (blockIdx.x >> 3) * RPB;

    const float* cbk = cb + (size_t)k * CB * DIM;

    // ---- x A-fragments (4 M-tiles x 3 planes, 48 VGPRs), loaded once ----
    // A-frag layout (16x16x32): row = lane&15, k = (lane>>4)*8 + j
    bf16x8 xh[4], xm[4], xl[4];
#pragma unroll
    for (int mt = 0; mt < 4; ++mt) {
        const int row = n0 + w * 64 + mt * 16 + l15;
        const float* xp = x + ((size_t)row * NCB + k) * DIM + l4 * 8;
        split3(*(const f32x4*)xp, *(const f32x4*)(xp + 4), &xh[mt], &xm[mt],
               &xl[mt]);
    }

    // ---- stage pass-0 c planes (B-frag pattern: col=l15, k=l4*8+j) ----
#pragma unroll
    for (int rd = 0; rd < 4; ++rd) {
        const int eLoc = w * 64 + rd * 16 + l15;
        const float* src = cbk + (size_t)eLoc * DIM + l4 * 8;
        bf16x8 h, m, l;
        split3(*(const f32x4*)src, *(const f32x4*)(src + 4), &h, &m, &l);
        const int so = eLoc * DIM + l4 * 8;
        *(bf16x8*)&cH[so] = h;
        *(bf16x8*)&cM[so] = m;
        *(bf16x8*)&cL[so] = l;
    }
    sCq[tid] = csqb[(size_t)k * CB + tid];
    sCq[tid + 512] = csqb[(size_t)k * CB + tid + 512];
    __syncthreads();  // staged; NO stores outstanding yet (cheap drain)

    // ---- prefetch pass-1 entries into registers (OLDEST FIFO entries) ----
    f32x4 pf[4][2];
#pragma unroll
    for (int rd = 0; rd < 4; ++rd) {
        const int eLoc = w * 64 + rd * 16 + l15;
        const float* src = cbk + (size_t)(EPP + eLoc) * DIM + l4 * 8;
        pf[rd][0] = *(const f32x4*)src;
        pf[rd][1] = *(const f32x4*)(src + 4);
    }

    float best[4][4];
    int bidx[4][4];
#pragma unroll
    for (int mt = 0; mt < 4; ++mt)
#pragma unroll
        for (int r = 0; r < 4; ++r) {
            best[mt][r] = 3.4028235e38f;
            bidx[mt][r] = 0;
        }

    const f32x4 z4 = {0.f, 0.f, 0.f, 0.f};

    for (int p = 0; p < 2; ++p) {
        if (p) {
            LGK_BARRIER();  // all waves done READING pass-0 planes (no vm drain)
#pragma unroll
            for (int rd = 0; rd < 4; ++rd) {
                const int eLoc = w * 64 + rd * 16 + l15;
                bf16x8 h, m, l;
                // counted vmcnt: >=65 of the 128 later stores retired => the
                // prefetch loads (oldest) are long done; stores keep flying
                split3(pf[rd][0], pf[rd][1], &h, &m, &l);
                const int so = eLoc * DIM + l4 * 8;
                *(bf16x8*)&cH[so] = h;
                *(bf16x8*)&cM[so] = m;
                *(bf16x8*)&cL[so] = l;
            }
            LGK_BARRIER();  // restage visible to all waves (no vm drain)
        }

#pragma unroll 2
        for (int tt = 0; tt < TPP; ++tt) {
            // zero-fill: one full one_hot row of this wave per tile (4 KB)
            {
                f32x4* rp = (f32x4*)onehot +
                            ((size_t)(n0 + w * 64 + p * 32 + tt) * NCB + k) *
                                256;
#pragma unroll
                for (int j = 0; j < 4; ++j) rp[j * 64 + lane] = z4;
            }

            const int so = (tt * 16 + l15) * DIM + l4 * 8;
            const bf16x8 ch = *(const bf16x8*)&cH[so];
            const bf16x8 cm = *(const bf16x8*)&cM[so];
            const bf16x8 cl = *(const bf16x8*)&cL[so];
            const float cqv = sCq[p * EPP + tt * 16 + l15];
            const int eg = p * EPP + tt * 16 + l15;

#pragma unroll
            for (int mt = 0; mt < 4; ++mt) {
                f32x4 acc = {0.f, 0.f, 0.f, 0.f};
                acc = __builtin_amdgcn_mfma_f32_16x16x32_bf16(xh[mt], ch, acc,
                                                              0, 0, 0);
                acc = __builtin_amdgcn_mfma_f32_16x16x32_bf16(xh[mt], cm, acc,
                                                              0, 0, 0);
                acc = __builtin_amdgcn_mfma_f32_16x16x32_bf16(xm[mt], ch, acc,
                                                              0, 0, 0);
                acc = __builtin_amdgcn_mfma_f32_16x16x32_bf16(xm[mt], cm, acc,
                                                              0, 0, 0);
                acc = __builtin_amdgcn_mfma_f32_16x16x32_bf16(xh[mt], cl, acc,
                                                              0, 0, 0);
                acc = __builtin_amdgcn_mfma_f32_16x16x32_bf16(xl[mt], ch, acc,
                                                              0, 0, 0);
                // C/D: col(entry)=lane&15, row=(lane>>4)*4+r  [HW-verified]
#pragma unroll
                for (int r = 0; r < 4; ++r) {
                    const float dist = fmaf(-2.f, acc[r], cqv);
                    if (dist < best[mt][r]) {  // strict <: first occurrence
                        best[mt][r] = dist;
                        bidx[mt][r] = eg;
                    }
                }
            }
        }
    }

    // ---- cross-lane reduce over the 16 entry-lanes (tie -> lower idx) ----
#pragma unroll
    for (int mt = 0; mt < 4; ++mt)
#pragma unroll
        for (int r = 0; r < 4; ++r) {
            float b = best[mt][r];
            int ix = bidx[mt][r];
#pragma unroll
            for (int mask = 1; mask <= 8; mask <<= 1) {
                const float ob = __shfl_xor(b, mask, 64);
                const int oi = __shfl_xor(ix, mask, 64);
                if (ob < b || (ob == b && oi < ix)) {
                    b = ob;
                    ix = oi;
                }
            }
            if (l15 == 0)
                sIdx[w * 64 + mt * 16 + l4 * 4 + r] = (unsigned short)ix;
        }

    // same-wave LDS handoff (lgkmcnt auto)
    const int bx = sIdx[w * 64 + lane];
    const int n = n0 + w * 64 + lane;

    // idx + x_hat issued BEFORE the drain (independent of the zeros)
    idxf[(size_t)n * NCB + k] = (float)bx;
    const f32x4* srcv = (const f32x4*)(cbk + (size_t)bx * DIM);
    f32x4* dst = (f32x4*)(xhat + ((size_t)n * NCB + k) * DIM);
#pragma unroll
    for (int j = 0; j < 8; ++j) dst[j] = srcv[j];

    // drain this wave's zero-stores (its own 64 rows), then the 1.0 scatter
    asm volatile("s_waitcnt vmcnt(0)" ::: "memory");
    onehot[((size_t)n * NCB + k) * CB + bx] = 1.0f;
}

extern "C" void kernel_launch(void* const* d_in, const int* in_sizes, int n_in,
                              void* d_out, int out_size, void* d_ws,
                              size_t ws_size, hipStream_t stream) {
    const float* x = (const float*)d_in[0];
    const float* cb = (const float*)d_in[1];
    const float* rb = (const float*)d_in[2];

    float* out = (float*)d_out;
    float* xhat = out;                             // N*NCB*DIM
    float* onehot = out + (size_t)NN * NCB * DIM;  // N*NCB*CB
    float* idxf = onehot + (size_t)NN * NCB * CB;  // N*NCB

    float* csqb = (float*)d_ws;  // 32 KB

    vq_csq<<<(NCB * CB + 255) / 256, 256, 0, stream>>>(cb, rb, csqb);
    vq_fused<<<(NN / RPB) * NCB, 512, 0, stream>>>(x, cb, csqb, xhat, onehot,
                                                   idxf);
}